// Round 6
// baseline (198.815 us; speedup 1.0000x reference)
//
#include <hip/hip_runtime.h>
#include <hip/hip_bf16.h>
#include <stdint.h>
#include <math.h>

#define H_HT 26
#define W_HT 122
#define NPIX (H_HT * W_HT)   // 3172
#define NA 60
#define NR 125
#define NROW (NPIX * NA)     // 190320
#define NB 32
#define NC 4
#define NBC (NB * NC)        // 128
#define PH 288
#define PW 800

#define PRED_BLKS ((NROW + 255) / 256)   // 744 predict blocks
#define GT_BLKS ((NPIX + 1) / 2)         // 1586 transpose-gather blocks (2 pix x 128 bc)

// ---- workspace layout (bytes) ----
#define WS_RI    0                         // uint8 [60*3172]        190320
#define WS_OFF   190336                    // int32 [60*126]          30240
#define WS_LIST  220608                    // uint16[60*3172]        380640
#define WS_PREDT 601280                    // float [3172*128]      1624064
#define WS_PV    2225344                   // float [128*60]          30720
#define WS_PI    2256064                   // int32 [128*60]          30720

// ---------------- Kernel A: predict+verify rho index, and pred_T gather -----
// Blocks [0, PRED_BLKS): rho = xs*cos + ys*sin in numpy f64 op order; verify
// the predicted one-hot slot with one read (exactly one 1.0 per row), rare
// fallback row scan. Blocks [PRED_BLKS, +GT_BLKS): transpose-gather
// pred_T[pixel][bc] -- divergent reads, fully coalesced writes.
__global__ __launch_bounds__(256) void prep(const float* __restrict__ vote,
                                            const float* __restrict__ pred,
                                            uint8_t* __restrict__ ri,
                                            float* __restrict__ pred_T) {
    const int tid = threadIdx.x;
    if (blockIdx.x < PRED_BLKS) {
        __shared__ double s_c[NA], s_s[NA];
        if (tid < NA) {
            double t = (double)(tid * 3) * 0.017453292519943295;  // deg2rad
            s_c[tid] = cos(t);
            s_s[tid] = sin(t);
        }
        __syncthreads();
        int row = blockIdx.x * 256 + tid;            // row = pix*60 + a
        if (row >= NROW) return;
        int pix = row / NA;
        int a   = row - pix * NA;
        int h   = pix / W_HT;
        int w   = pix - h * W_HT;
        double xs = (double)w - 60.5;                // w - 122/2 + 0.5
        double ys = (double)h - 12.5;                // h - 26/2 + 0.5
        double rho = __dadd_rn(__dmul_rn(xs, s_c[a]), __dmul_rn(ys, s_s[a]));
        int r = (int)rint(rho) + NR / 2;             // half-even, + 62
        r = r < 0 ? 0 : (r > NR - 1 ? NR - 1 : r);
        const float* vrow = vote + (size_t)row * NR;
        if (vrow[r] == 0.0f) {
            for (int r2 = 0; r2 < NR; ++r2) {
                if (vrow[r2] != 0.0f) { r = r2; break; }
            }
        }
        ri[a * NPIX + pix] = (uint8_t)r;
    } else {
        const int bidx = blockIdx.x - PRED_BLKS;
        const int p  = bidx * 2 + (tid >> 7);
        const int bc = tid & 127;
        if (p < NPIX) {
            const float C1 = (float)(288.0 / 26.0);
            const float C2 = (float)(800.0 / 122.0);
            int h = p / W_HT;
            int w = p - h * W_HT;
            int hi = (int)floorf((float)h * C1);
            int wi = (int)floorf((float)w * C2);
            pred_T[p * NBC + bc] = pred[((size_t)bc * PH + hi) * PW + wi];
        }
    }
}

// ---------------- Kernel B: invert ri into CSR bucket lists per angle -------
__global__ __launch_bounds__(256) void build_csr(const uint8_t* __restrict__ ri,
                                                 int* __restrict__ off,
                                                 uint16_t* __restrict__ list) {
    __shared__ int s_cnt[NR];
    __shared__ int s_pre[NR + 1];
    __shared__ int s_cur[NR];
    const int a = blockIdx.x;
    const int tid = threadIdx.x;
    for (int i = tid; i < NR; i += 256) s_cnt[i] = 0;
    __syncthreads();
    for (int p = tid; p < NPIX; p += 256)
        atomicAdd(&s_cnt[ri[a * NPIX + p]], 1);
    __syncthreads();
    if (tid == 0) {
        int s = 0;
        for (int r = 0; r < NR; ++r) { s_pre[r] = s; s += s_cnt[r]; }
        s_pre[NR] = s;
    }
    __syncthreads();
    for (int r = tid; r < NR + 1; r += 256) off[a * (NR + 1) + r] = s_pre[r];
    for (int r = tid; r < NR; r += 256) s_cur[r] = s_pre[r];
    __syncthreads();
    for (int p = tid; p < NPIX; p += 256) {
        int r = ri[a * NPIX + p];
        int slot = atomicAdd(&s_cur[r], 1);
        list[a * NPIX + slot] = (uint16_t)p;
    }
}

// ---------------- Kernel C: transposed hough -------------------------------
// Block = (angle, bc-half). Lane = bc. Wave q handles bins [q*32, ...).
// Element loop: list entry uniform (LDS broadcast), pred_T read coalesced
// (64 lanes x 4B contiguous). Per-lane running argmax; LDS reduce over waves.
__global__ __launch_bounds__(256) void hough_T(const float* __restrict__ pred_T,
                                               const int* __restrict__ off,
                                               const uint16_t* __restrict__ list,
                                               float* __restrict__ pv,
                                               int* __restrict__ pi) {
    __shared__ uint16_t s_list[NPIX];
    __shared__ int      s_off[NR + 1];
    __shared__ float    s_v[4][64];
    __shared__ int      s_i[4][64];

    const int a    = blockIdx.x >> 1;
    const int half = blockIdx.x & 1;
    const int tid  = threadIdx.x;
    const int q    = tid >> 6;       // wave 0..3
    const int lane = tid & 63;
    const int bc   = half * 64 + lane;

    {   // stage this angle's list (coalesced as uint32) + offsets
        const uint32_t* src = reinterpret_cast<const uint32_t*>(list + a * NPIX);
        uint32_t* dst = reinterpret_cast<uint32_t*>(s_list);
        for (int i = tid; i < NPIX / 2; i += 256) dst[i] = src[i];
        for (int r = tid; r < NR + 1; r += 256) s_off[r] = off[a * (NR + 1) + r];
    }
    __syncthreads();

    const int r0 = q * 32;
    const int r1 = (r0 + 32 < NR) ? r0 + 32 : NR;
    float bestv = -1.0f; int besti = 0x7fffffff;
    int j = s_off[r0];
    for (int r = r0; r < r1; ++r) {
        int jend = s_off[r + 1];
        float s0 = 0.0f, s1 = 0.0f;
        for (; j + 1 < jend; j += 2) {
            s0 += pred_T[(int)s_list[j] * NBC + bc];
            s1 += pred_T[(int)s_list[j + 1] * NBC + bc];
        }
        if (j < jend) { s0 += pred_T[(int)s_list[j] * NBC + bc]; ++j; }
        float s = s0 + s1;
        if (s > bestv) { bestv = s; besti = a * NR + r; }
    }
    s_v[q][lane] = bestv; s_i[q][lane] = besti;
    __syncthreads();
    if (q == 0) {
        float bv = s_v[0][lane]; int bi = s_i[0][lane];
#pragma unroll
        for (int qq = 1; qq < 4; ++qq) {
            float ov = s_v[qq][lane]; int oi = s_i[qq][lane];
            if (ov > bv || (ov == bv && oi < bi)) { bv = ov; bi = oi; }
        }
        pv[bc * NA + a] = bv;
        pi[bc * NA + a] = bi;
    }
}

// ---------------- Kernel D: final argmax + gather + L1-normalize + loss -----
__global__ __launch_bounds__(64) void loss_kernel(const float* __restrict__ ht,
                                                  const float* __restrict__ pexist,
                                                  const float* __restrict__ pv,
                                                  const int* __restrict__ pi,
                                                  float* __restrict__ out) {
    const int b = blockIdx.x;
    const int l = threadIdx.x;
    const int p = l >> 2;     // pair 0..15
    const int s = l & 3;      // sub-lane within pair
    const int c = p >> 2;     // channel for ht
    const int k = p & 3;      // channel for idx/exist

    const int bck = b * 4 + k;
    // each of the 4 sub-lanes scans 15 angles (ascending), then xor-combine
    float bv = -1.0f; int bi = 0x7fffffff;
    for (int t = 0; t < 15; ++t) {
        int a = s * 15 + t;
        float v = pv[bck * NA + a];
        int   i = pi[bck * NA + a];
        if (v > bv || (v == bv && i < bi)) { bv = v; bi = i; }
    }
#pragma unroll
    for (int m = 1; m < 4; m <<= 1) {
        float ov = __shfl_xor(bv, m);
        int   oi = __shfl_xor(bi, m);
        if (ov > bv || (ov == bv && oi < bi)) { bv = ov; bi = oi; }
    }
    int fidx = bi;

    int a0 = fidx / NR;
    int r  = fidx - a0 * NR;
    const float* htc = ht + (size_t)((b * 4 + c) * NA) * NR;

    float acc = 0.0f;
    for (int a = s; a < NA; a += 4) acc += fabsf(htc[a * NR + r]);
    acc += __shfl_xor(acc, 1);
    acc += __shfl_xor(acc, 2);

    float term = 0.0f;
    if (s == 0) {
        float l1 = fmaxf(acc, 1e-12f);
        float gg = htc[a0 * NR + r] / l1;
        float ex = (pexist[b * 4 + k] > 0.9f) ? 1.0f : 0.0f;
        term = -logf(gg + 1e-12f) * ex;
    }
    for (int offt = 32; offt > 0; offt >>= 1) term += __shfl_down(term, offt);
    if (l == 0) out[b] = term * (1.0f / 16.0f);
}

extern "C" void kernel_launch(void* const* d_in, const int* in_sizes, int n_in,
                              void* d_out, int out_size, void* d_ws, size_t ws_size,
                              hipStream_t stream) {
    const float* ht     = (const float*)d_in[0];
    const float* pred   = (const float*)d_in[1];
    const float* pexist = (const float*)d_in[2];
    const float* vote   = (const float*)d_in[3];

    char* ws = (char*)d_ws;
    uint8_t*  ri     = (uint8_t*) (ws + WS_RI);
    int*      off    = (int*)     (ws + WS_OFF);
    uint16_t* list   = (uint16_t*)(ws + WS_LIST);
    float*    pred_T = (float*)   (ws + WS_PREDT);
    float*    pv     = (float*)   (ws + WS_PV);
    int*      pi     = (int*)     (ws + WS_PI);

    prep<<<PRED_BLKS + GT_BLKS, 256, 0, stream>>>(vote, pred, ri, pred_T);
    build_csr<<<NA, 256, 0, stream>>>(ri, off, list);
    hough_T<<<NA * 2, 256, 0, stream>>>(pred_T, off, list, pv, pi);
    loss_kernel<<<NB, 64, 0, stream>>>(ht, pexist, pv, pi, (float*)d_out);
}

// Round 7
// 68.982 us; speedup vs baseline: 2.8821x; 2.8821x over previous
//
#include <hip/hip_runtime.h>
#include <hip/hip_bf16.h>
#include <stdint.h>
#include <math.h>

#define H_HT 26
#define W_HT 122
#define NPIX (H_HT * W_HT)   // 3172
#define NA 60
#define NR 125
#define NROW (NPIX * NA)     // 190320
#define NB 32
#define NC 4
#define NBC (NB * NC)        // 128
#define PH 288
#define PW 800

#define PRED_BLKS ((NROW + 255) / 256)   // 744 predict blocks
#define GT_BLKS ((NPIX + 1) / 2)         // 1586 transpose-gather blocks
#define ZERO_BLKS 4

// ---- workspace layout (bytes) ----
#define WS_RI    0                         // uint8 [60*3172]        190320
#define WS_OFF   190336                    // int32 [60*126]          30240
#define WS_LIST  220608                    // uint16[60*3172]        380640
#define WS_PREDT 601280                    // float [3172*128]      1624064
#define WS_PVP   2225344                   // u64   [128*60]          61440

// ---------------- Kernel A: predict+verify rho index, pred_T gather, zero ---
__global__ __launch_bounds__(256) void prep(const float* __restrict__ vote,
                                            const float* __restrict__ pred,
                                            uint8_t* __restrict__ ri,
                                            float* __restrict__ pred_T,
                                            unsigned long long* __restrict__ pvp) {
    const int tid = threadIdx.x;
    if (blockIdx.x < PRED_BLKS) {
        __shared__ double s_c[NA], s_s[NA];
        if (tid < NA) {
            double t = (double)(tid * 3) * 0.017453292519943295;  // deg2rad
            s_c[tid] = cos(t);
            s_s[tid] = sin(t);
        }
        __syncthreads();
        int row = blockIdx.x * 256 + tid;            // row = pix*60 + a
        if (row >= NROW) return;
        int pix = row / NA;
        int a   = row - pix * NA;
        int h   = pix / W_HT;
        int w   = pix - h * W_HT;
        double xs = (double)w - 60.5;                // w - 122/2 + 0.5
        double ys = (double)h - 12.5;                // h - 26/2 + 0.5
        double rho = __dadd_rn(__dmul_rn(xs, s_c[a]), __dmul_rn(ys, s_s[a]));
        int r = (int)rint(rho) + NR / 2;             // half-even, + 62
        r = r < 0 ? 0 : (r > NR - 1 ? NR - 1 : r);
        const float* vrow = vote + (size_t)row * NR;
        if (vrow[r] == 0.0f) {
            for (int r2 = 0; r2 < NR; ++r2) {
                if (vrow[r2] != 0.0f) { r = r2; break; }
            }
        }
        ri[a * NPIX + pix] = (uint8_t)r;
    } else if (blockIdx.x < PRED_BLKS + GT_BLKS) {
        const int bidx = blockIdx.x - PRED_BLKS;
        const int p  = bidx * 2 + (tid >> 7);
        const int bc = tid & 127;
        if (p < NPIX) {
            const float C1 = (float)(288.0 / 26.0);
            const float C2 = (float)(800.0 / 122.0);
            int h = p / W_HT;
            int w = p - h * W_HT;
            int hi = (int)floorf((float)h * C1);
            int wi = (int)floorf((float)w * C2);
            pred_T[p * NBC + bc] = pred[((size_t)bc * PH + hi) * PW + wi];
        }
    } else {
        int i0 = (blockIdx.x - PRED_BLKS - GT_BLKS) * 256 + tid;
        for (int i = i0; i < NA * NBC; i += ZERO_BLKS * 256) pvp[i] = 0ull;
    }
}

// ---------------- Kernel B: invert ri into CSR bucket lists per angle -------
__global__ __launch_bounds__(256) void build_csr(const uint8_t* __restrict__ ri,
                                                 int* __restrict__ off,
                                                 uint16_t* __restrict__ list) {
    __shared__ int s_cnt[NR];
    __shared__ int s_pre[NR + 1];
    __shared__ int s_cur[NR];
    const int a = blockIdx.x;
    const int tid = threadIdx.x;
    for (int i = tid; i < NR; i += 256) s_cnt[i] = 0;
    __syncthreads();
    for (int p = tid; p < NPIX; p += 256)
        atomicAdd(&s_cnt[ri[a * NPIX + p]], 1);
    __syncthreads();
    if (tid == 0) {
        int s = 0;
        for (int r = 0; r < NR; ++r) { s_pre[r] = s; s += s_cnt[r]; }
        s_pre[NR] = s;
    }
    __syncthreads();
    for (int r = tid; r < NR + 1; r += 256) off[a * (NR + 1) + r] = s_pre[r];
    for (int r = tid; r < NR; r += 256) s_cur[r] = s_pre[r];
    __syncthreads();
    for (int p = tid; p < NPIX; p += 256) {
        int r = ri[a * NPIX + p];
        int slot = atomicAdd(&s_cur[r], 1);
        list[a * NPIX + slot] = (uint16_t)p;
    }
}

// ---------------- Kernel C: transposed hough, quarter-split + 8-wide ILP ----
// Block = (angle, bc-half, rho-quarter). Lane = bc. Wave wq owns 8 bins.
// 8 independent pred_T loads in flight per iteration; per-lane argmax;
// quarters merged via packed atomicMax (max value, tie -> smaller bin).
__global__ __launch_bounds__(256) void hough_T2(const float* __restrict__ pred_T,
                                                const int* __restrict__ off,
                                                const uint16_t* __restrict__ list,
                                                unsigned long long* __restrict__ pvp) {
    __shared__ uint16_t s_list[NPIX];
    __shared__ int s_off[33];

    const int blk     = blockIdx.x;
    const int a       = blk >> 3;
    const int half    = (blk >> 2) & 1;
    const int quarter = blk & 3;
    const int tid     = threadIdx.x;
    const int wq      = tid >> 6;
    const int lane    = tid & 63;
    const int bc      = half * 64 + lane;

    const int r0 = quarter * 32;
    const int r1 = (r0 + 32 < NR) ? r0 + 32 : NR;
    const int nb = r1 - r0;
    if (tid <= nb) s_off[tid] = off[a * (NR + 1) + r0 + tid];
    __syncthreads();
    const int jb   = s_off[0];
    const int jtot = s_off[nb] - jb;
    for (int i = tid; i < jtot; i += 256) s_list[i] = list[a * NPIX + jb + i];
    __syncthreads();

    float bestv = -1.0f; int besti = 0x7fffffff;
    const int rb0 = r0 + wq * 8;
    const int rb1 = (rb0 + 8 < r1) ? rb0 + 8 : r1;
    for (int r = rb0; r < rb1; ++r) {
        int o0 = s_off[r - r0] - jb;
        int o1 = s_off[r - r0 + 1] - jb;
        float s0 = 0, s1 = 0, s2 = 0, s3 = 0, s4 = 0, s5 = 0, s6 = 0, s7 = 0;
        int j = o0;
        for (; j + 8 <= o1; j += 8) {
            int p0 = s_list[j],     p1 = s_list[j + 1], p2 = s_list[j + 2], p3 = s_list[j + 3];
            int p4 = s_list[j + 4], p5 = s_list[j + 5], p6 = s_list[j + 6], p7 = s_list[j + 7];
            s0 += pred_T[p0 * NBC + bc]; s1 += pred_T[p1 * NBC + bc];
            s2 += pred_T[p2 * NBC + bc]; s3 += pred_T[p3 * NBC + bc];
            s4 += pred_T[p4 * NBC + bc]; s5 += pred_T[p5 * NBC + bc];
            s6 += pred_T[p6 * NBC + bc]; s7 += pred_T[p7 * NBC + bc];
        }
        for (; j < o1; ++j) s0 += pred_T[(int)s_list[j] * NBC + bc];
        float s = ((s0 + s1) + (s2 + s3)) + ((s4 + s5) + (s6 + s7));
        if (s > bestv) { bestv = s; besti = a * NR + r; }
    }
    if (rb0 < rb1) {
        unsigned int fb = __float_as_uint(bestv);   // bestv >= 0 here
        unsigned long long enc = ((unsigned long long)fb << 32)
                               | (unsigned long long)(65535 - besti);
        atomicMax(&pvp[bc * NA + a], enc);
    }
}

// ---------------- Kernel D: final argmax + gather + L1-normalize + loss -----
__global__ __launch_bounds__(64) void loss_kernel(const float* __restrict__ ht,
                                                  const float* __restrict__ pexist,
                                                  const unsigned long long* __restrict__ pvp,
                                                  float* __restrict__ out) {
    const int b = blockIdx.x;
    const int l = threadIdx.x;
    const int p = l >> 2;     // pair 0..15
    const int s = l & 3;      // sub-lane within pair
    const int c = p >> 2;     // channel for ht
    const int k = p & 3;      // channel for idx/exist

    const int bck = b * 4 + k;
    unsigned long long be = 0ull;
    for (int t = 0; t < 15; ++t) {
        int a = s * 15 + t;
        unsigned long long e = pvp[bck * NA + a];
        if (e > be) be = e;
    }
#pragma unroll
    for (int m = 1; m < 4; m <<= 1) {
        unsigned long long oe = __shfl_xor(be, m);
        if (oe > be) be = oe;
    }
    int fidx = 65535 - (int)(be & 0xFFFFull);

    int a0 = fidx / NR;
    int r  = fidx - a0 * NR;
    const float* htc = ht + (size_t)((b * 4 + c) * NA) * NR;

    float acc = 0.0f;
    for (int a = s; a < NA; a += 4) acc += fabsf(htc[a * NR + r]);
    acc += __shfl_xor(acc, 1);
    acc += __shfl_xor(acc, 2);

    float term = 0.0f;
    if (s == 0) {
        float l1 = fmaxf(acc, 1e-12f);
        float gg = htc[a0 * NR + r] / l1;
        float ex = (pexist[b * 4 + k] > 0.9f) ? 1.0f : 0.0f;
        term = -logf(gg + 1e-12f) * ex;
    }
    for (int offt = 32; offt > 0; offt >>= 1) term += __shfl_down(term, offt);
    if (l == 0) out[b] = term * (1.0f / 16.0f);
}

extern "C" void kernel_launch(void* const* d_in, const int* in_sizes, int n_in,
                              void* d_out, int out_size, void* d_ws, size_t ws_size,
                              hipStream_t stream) {
    const float* ht     = (const float*)d_in[0];
    const float* pred   = (const float*)d_in[1];
    const float* pexist = (const float*)d_in[2];
    const float* vote   = (const float*)d_in[3];

    char* ws = (char*)d_ws;
    uint8_t*  ri     = (uint8_t*) (ws + WS_RI);
    int*      off    = (int*)     (ws + WS_OFF);
    uint16_t* list   = (uint16_t*)(ws + WS_LIST);
    float*    pred_T = (float*)   (ws + WS_PREDT);
    unsigned long long* pvp = (unsigned long long*)(ws + WS_PVP);

    prep<<<PRED_BLKS + GT_BLKS + ZERO_BLKS, 256, 0, stream>>>(vote, pred, ri, pred_T, pvp);
    build_csr<<<NA, 256, 0, stream>>>(ri, off, list);
    hough_T2<<<NA * 2 * 4, 256, 0, stream>>>(pred_T, off, list, pvp);
    loss_kernel<<<NB, 64, 0, stream>>>(ht, pexist, pvp, (float*)d_out);
}

// Round 8
// 54.057 us; speedup vs baseline: 3.6779x; 1.2761x over previous
//
#include <hip/hip_runtime.h>
#include <hip/hip_bf16.h>
#include <stdint.h>
#include <math.h>

#define H_HT 26
#define W_HT 122
#define NPIX (H_HT * W_HT)   // 3172
#define NA 60
#define NR 125
#define NROW (NPIX * NA)     // 190320
#define NB 32
#define NC 4
#define NBC (NB * NC)        // 128
#define PH 288
#define PW 800

#define PRED_BLKS ((NROW + 255) / 256)   // 744 predict blocks
#define GT_BLKS ((NPIX + 1) / 2)         // 1586 transpose-gather blocks
#define ZERO_BLKS 4

// ---- workspace layout (bytes) ----
#define WS_RI    0                         // uint8 [60*3172]        190320
#define WS_OFF   190336                    // int32 [60*126]          30240
#define WS_LIST  220608                    // uint16[60*3172]        380640
#define WS_PREDT 601280                    // float [3172*128]      1624064
#define WS_PVP   2225344                   // u64   [128*60]          61440

// ---------------- Kernel A: predict+verify rho index, pred_T gather, zero ---
__global__ __launch_bounds__(256) void prep(const float* __restrict__ vote,
                                            const float* __restrict__ pred,
                                            uint8_t* __restrict__ ri,
                                            float* __restrict__ pred_T,
                                            unsigned long long* __restrict__ pvp) {
    const int tid = threadIdx.x;
    if (blockIdx.x < PRED_BLKS) {
        __shared__ double s_c[NA], s_s[NA];
        if (tid < NA) {
            double t = (double)(tid * 3) * 0.017453292519943295;  // deg2rad
            s_c[tid] = cos(t);
            s_s[tid] = sin(t);
        }
        __syncthreads();
        int row = blockIdx.x * 256 + tid;            // row = pix*60 + a
        if (row >= NROW) return;
        int pix = row / NA;
        int a   = row - pix * NA;
        int h   = pix / W_HT;
        int w   = pix - h * W_HT;
        double xs = (double)w - 60.5;                // w - 122/2 + 0.5
        double ys = (double)h - 12.5;                // h - 26/2 + 0.5
        double rho = __dadd_rn(__dmul_rn(xs, s_c[a]), __dmul_rn(ys, s_s[a]));
        int r = (int)rint(rho) + NR / 2;             // half-even, + 62
        r = r < 0 ? 0 : (r > NR - 1 ? NR - 1 : r);
        const float* vrow = vote + (size_t)row * NR;
        if (vrow[r] == 0.0f) {
            for (int r2 = 0; r2 < NR; ++r2) {
                if (vrow[r2] != 0.0f) { r = r2; break; }
            }
        }
        ri[a * NPIX + pix] = (uint8_t)r;
    } else if (blockIdx.x < PRED_BLKS + GT_BLKS) {
        const int bidx = blockIdx.x - PRED_BLKS;
        const int p  = bidx * 2 + (tid >> 7);
        const int bc = tid & 127;
        if (p < NPIX) {
            const float C1 = (float)(288.0 / 26.0);
            const float C2 = (float)(800.0 / 122.0);
            int h = p / W_HT;
            int w = p - h * W_HT;
            int hi = (int)floorf((float)h * C1);
            int wi = (int)floorf((float)w * C2);
            pred_T[p * NBC + bc] = pred[((size_t)bc * PH + hi) * PW + wi];
        }
    } else {
        int i0 = (blockIdx.x - PRED_BLKS - GT_BLKS) * 256 + tid;
        for (int i = i0; i < NA * NBC; i += ZERO_BLKS * 256) pvp[i] = 0ull;
    }
}

// ---------------- Kernel B: invert ri into CSR bucket lists per angle -------
// Parallel Hillis-Steele prefix scan replaces the serial tid-0 loop.
__global__ __launch_bounds__(256) void build_csr(const uint8_t* __restrict__ ri,
                                                 int* __restrict__ off,
                                                 uint16_t* __restrict__ list) {
    __shared__ int s_cnt[NR];
    __shared__ int sc[2][NR];
    __shared__ int s_pre[NR + 1];
    __shared__ int s_cur[NR];
    const int a = blockIdx.x;
    const int tid = threadIdx.x;
    for (int i = tid; i < NR; i += 256) s_cnt[i] = 0;
    __syncthreads();
    for (int p = tid; p < NPIX; p += 256)
        atomicAdd(&s_cnt[ri[a * NPIX + p]], 1);
    __syncthreads();
    if (tid < NR) sc[0][tid] = s_cnt[tid];
    __syncthreads();
    int pin = 0;
    for (int d = 1; d < NR; d <<= 1) {
        if (tid < NR) {
            int v = sc[pin][tid];
            if (tid >= d) v += sc[pin][tid - d];
            sc[pin ^ 1][tid] = v;
        }
        __syncthreads();
        pin ^= 1;
    }
    if (tid == 0) s_pre[0] = 0;
    if (tid < NR) s_pre[tid + 1] = sc[pin][tid];
    __syncthreads();
    for (int r = tid; r < NR + 1; r += 256) off[a * (NR + 1) + r] = s_pre[r];
    for (int r = tid; r < NR; r += 256) s_cur[r] = s_pre[r];
    __syncthreads();
    for (int p = tid; p < NPIX; p += 256) {
        int r = ri[a * NPIX + p];
        int slot = atomicAdd(&s_cur[r], 1);
        list[a * NPIX + slot] = (uint16_t)p;
    }
}

// ---------------- Kernel C: transposed hough, strided bins + 8-wide ILP -----
// Block = (angle, bc-half, q). Lane = bc. Wave w handles bins r = q*4+w + 16t
// (interleaved rho -> clustered heavy bins spread across all 16 wave-groups).
// Full angle list staged in LDS; 8 independent pred_T loads in flight;
// per-wave running argmax; merge via packed atomicMax (tie -> smaller bin).
__global__ __launch_bounds__(256) void hough_T3(const float* __restrict__ pred_T,
                                                const int* __restrict__ off,
                                                const uint16_t* __restrict__ list,
                                                unsigned long long* __restrict__ pvp) {
    __shared__ uint16_t s_list[NPIX];    // 6344 B
    __shared__ int s_off[NR + 1];

    const int blk  = blockIdx.x;
    const int a    = blk >> 3;
    const int half = (blk >> 2) & 1;
    const int q    = blk & 3;
    const int tid  = threadIdx.x;
    const int w    = tid >> 6;
    const int lane = tid & 63;
    const int bc   = half * 64 + lane;

    {   // stage full angle list (coalesced as uint32) + offsets
        const uint32_t* src = reinterpret_cast<const uint32_t*>(list + a * NPIX);
        uint32_t* dst = reinterpret_cast<uint32_t*>(s_list);
        for (int i = tid; i < NPIX / 2; i += 256) dst[i] = src[i];
        for (int r = tid; r < NR + 1; r += 256) s_off[r] = off[a * (NR + 1) + r];
    }
    __syncthreads();

    float bestv = -1.0f; int besti = 0x7fffffff;
    for (int r = q * 4 + w; r < NR; r += 16) {
        int o0 = s_off[r];
        int o1 = s_off[r + 1];
        float s0 = 0, s1 = 0, s2 = 0, s3 = 0, s4 = 0, s5 = 0, s6 = 0, s7 = 0;
        int j = o0;
        for (; j + 8 <= o1; j += 8) {
            int p0 = s_list[j],     p1 = s_list[j + 1], p2 = s_list[j + 2], p3 = s_list[j + 3];
            int p4 = s_list[j + 4], p5 = s_list[j + 5], p6 = s_list[j + 6], p7 = s_list[j + 7];
            s0 += pred_T[p0 * NBC + bc]; s1 += pred_T[p1 * NBC + bc];
            s2 += pred_T[p2 * NBC + bc]; s3 += pred_T[p3 * NBC + bc];
            s4 += pred_T[p4 * NBC + bc]; s5 += pred_T[p5 * NBC + bc];
            s6 += pred_T[p6 * NBC + bc]; s7 += pred_T[p7 * NBC + bc];
        }
        for (; j < o1; ++j) s0 += pred_T[(int)s_list[j] * NBC + bc];
        float s = ((s0 + s1) + (s2 + s3)) + ((s4 + s5) + (s6 + s7));
        if (s > bestv) { bestv = s; besti = a * NR + r; }
    }
    unsigned int fb = __float_as_uint(bestv < 0.0f ? 0.0f : bestv);
    unsigned long long enc = ((unsigned long long)fb << 32)
                           | (unsigned long long)(65535 - besti);
    atomicMax(&pvp[bc * NA + a], enc);
}

// ---------------- Kernel D: final argmax + gather + L1-normalize + loss -----
__global__ __launch_bounds__(64) void loss_kernel(const float* __restrict__ ht,
                                                  const float* __restrict__ pexist,
                                                  const unsigned long long* __restrict__ pvp,
                                                  float* __restrict__ out) {
    const int b = blockIdx.x;
    const int l = threadIdx.x;
    const int p = l >> 2;     // pair 0..15
    const int s = l & 3;      // sub-lane within pair
    const int c = p >> 2;     // channel for ht
    const int k = p & 3;      // channel for idx/exist

    const int bck = b * 4 + k;
    unsigned long long be = 0ull;
    for (int t = 0; t < 15; ++t) {
        int a = s * 15 + t;
        unsigned long long e = pvp[bck * NA + a];
        if (e > be) be = e;
    }
#pragma unroll
    for (int m = 1; m < 4; m <<= 1) {
        unsigned long long oe = __shfl_xor(be, m);
        if (oe > be) be = oe;
    }
    int fidx = 65535 - (int)(be & 0xFFFFull);

    int a0 = fidx / NR;
    int r  = fidx - a0 * NR;
    const float* htc = ht + (size_t)((b * 4 + c) * NA) * NR;

    float acc = 0.0f;
    for (int a = s; a < NA; a += 4) acc += fabsf(htc[a * NR + r]);
    acc += __shfl_xor(acc, 1);
    acc += __shfl_xor(acc, 2);

    float term = 0.0f;
    if (s == 0) {
        float l1 = fmaxf(acc, 1e-12f);
        float gg = htc[a0 * NR + r] / l1;
        float ex = (pexist[b * 4 + k] > 0.9f) ? 1.0f : 0.0f;
        term = -logf(gg + 1e-12f) * ex;
    }
    for (int offt = 32; offt > 0; offt >>= 1) term += __shfl_down(term, offt);
    if (l == 0) out[b] = term * (1.0f / 16.0f);
}

extern "C" void kernel_launch(void* const* d_in, const int* in_sizes, int n_in,
                              void* d_out, int out_size, void* d_ws, size_t ws_size,
                              hipStream_t stream) {
    const float* ht     = (const float*)d_in[0];
    const float* pred   = (const float*)d_in[1];
    const float* pexist = (const float*)d_in[2];
    const float* vote   = (const float*)d_in[3];

    char* ws = (char*)d_ws;
    uint8_t*  ri     = (uint8_t*) (ws + WS_RI);
    int*      off    = (int*)     (ws + WS_OFF);
    uint16_t* list   = (uint16_t*)(ws + WS_LIST);
    float*    pred_T = (float*)   (ws + WS_PREDT);
    unsigned long long* pvp = (unsigned long long*)(ws + WS_PVP);

    prep<<<PRED_BLKS + GT_BLKS + ZERO_BLKS, 256, 0, stream>>>(vote, pred, ri, pred_T, pvp);
    build_csr<<<NA, 256, 0, stream>>>(ri, off, list);
    hough_T3<<<NA * 2 * 4, 256, 0, stream>>>(pred_T, off, list, pvp);
    loss_kernel<<<NB, 64, 0, stream>>>(ht, pexist, pvp, (float*)d_out);
}

// Round 9
// 52.206 us; speedup vs baseline: 3.8082x; 1.0354x over previous
//
#include <hip/hip_runtime.h>
#include <hip/hip_bf16.h>
#include <stdint.h>
#include <math.h>

#define H_HT 26
#define W_HT 122
#define NPIX (H_HT * W_HT)   // 3172
#define NA 60
#define NR 125
#define NROW (NPIX * NA)     // 190320
#define NB 32
#define NC 4
#define NBC (NB * NC)        // 128
#define PH 288
#define PW 800
#define NSPLIT 16            // rho splits per angle; wave bins r = q*4+w + 64t

#define PRED_BLKS ((NROW + 255) / 256)   // 744 predict blocks
#define GT_BLKS ((NPIX + 1) / 2)         // 1586 transpose-gather blocks
#define ZERO_BLKS 4

// ---- workspace layout (bytes) ----
#define WS_RI    0                         // uint8 [60*3172]        190320
#define WS_OFF   190336                    // int32 [60*126]          30240
#define WS_LIST  220608                    // uint16[60*3172]        380640
#define WS_PREDT 601280                    // float [3172*128]      1624064
#define WS_PVP   2225344                   // u64   [128*60]          61440

// ---------------- Kernel A: guarded-predict rho index, pred_T gather, zero --
// f32 trig; |Δrho| vs numpy-f64 ≤ ~3e-5, so rint can only differ where
// frac(rho) is within 1e-3 of 0.5 -- only those rows read vote (verify +
// exact row-scan fallback). Unguarded rows provably match numpy.
__global__ __launch_bounds__(256) void prep(const float* __restrict__ vote,
                                            const float* __restrict__ pred,
                                            uint8_t* __restrict__ ri,
                                            float* __restrict__ pred_T,
                                            unsigned long long* __restrict__ pvp) {
    const int tid = threadIdx.x;
    if (blockIdx.x < PRED_BLKS) {
        int row = blockIdx.x * 256 + tid;            // row = pix*60 + a
        if (row >= NROW) return;
        int pix = row / NA;
        int a   = row - pix * NA;
        int h   = pix / W_HT;
        int w   = pix - h * W_HT;
        float xs = (float)w - 60.5f;                 // w - 122/2 + 0.5
        float ys = (float)h - 12.5f;                 // h - 26/2 + 0.5
        float t  = (float)(a * 3) * 0.017453292519943295f;
        float sn, cs;
        __sincosf(t, &sn, &cs);
        float rho = xs * cs + ys * sn;
        int r = (int)rintf(rho) + NR / 2;            // + 62
        r = r < 0 ? 0 : (r > NR - 1 ? NR - 1 : r);
        float dist = fabsf(rho - floorf(rho) - 0.5f);
        if (dist < 1e-3f) {                          // possible rint flip: verify
            const float* vrow = vote + (size_t)row * NR;
            if (vrow[r] == 0.0f) {
                for (int r2 = 0; r2 < NR; ++r2) {
                    if (vrow[r2] != 0.0f) { r = r2; break; }
                }
            }
        }
        ri[a * NPIX + pix] = (uint8_t)r;
    } else if (blockIdx.x < PRED_BLKS + GT_BLKS) {
        const int bidx = blockIdx.x - PRED_BLKS;
        const int p  = bidx * 2 + (tid >> 7);
        const int bc = tid & 127;
        if (p < NPIX) {
            const float C1 = (float)(288.0 / 26.0);
            const float C2 = (float)(800.0 / 122.0);
            int h = p / W_HT;
            int w = p - h * W_HT;
            int hi = (int)floorf((float)h * C1);
            int wi = (int)floorf((float)w * C2);
            pred_T[p * NBC + bc] = pred[((size_t)bc * PH + hi) * PW + wi];
        }
    } else {
        int i0 = (blockIdx.x - PRED_BLKS - GT_BLKS) * 256 + tid;
        for (int i = i0; i < NA * NBC; i += ZERO_BLKS * 256) pvp[i] = 0ull;
    }
}

// ---------------- Kernel B: invert ri into CSR bucket lists per angle -------
__global__ __launch_bounds__(256) void build_csr(const uint8_t* __restrict__ ri,
                                                 int* __restrict__ off,
                                                 uint16_t* __restrict__ list) {
    __shared__ int s_cnt[NR];
    __shared__ int sc[2][NR];
    __shared__ int s_pre[NR + 1];
    __shared__ int s_cur[NR];
    const int a = blockIdx.x;
    const int tid = threadIdx.x;
    for (int i = tid; i < NR; i += 256) s_cnt[i] = 0;
    __syncthreads();
    for (int p = tid; p < NPIX; p += 256)
        atomicAdd(&s_cnt[ri[a * NPIX + p]], 1);
    __syncthreads();
    if (tid < NR) sc[0][tid] = s_cnt[tid];
    __syncthreads();
    int pin = 0;
    for (int d = 1; d < NR; d <<= 1) {
        if (tid < NR) {
            int v = sc[pin][tid];
            if (tid >= d) v += sc[pin][tid - d];
            sc[pin ^ 1][tid] = v;
        }
        __syncthreads();
        pin ^= 1;
    }
    if (tid == 0) s_pre[0] = 0;
    if (tid < NR) s_pre[tid + 1] = sc[pin][tid];
    __syncthreads();
    for (int r = tid; r < NR + 1; r += 256) off[a * (NR + 1) + r] = s_pre[r];
    for (int r = tid; r < NR; r += 256) s_cur[r] = s_pre[r];
    __syncthreads();
    for (int p = tid; p < NPIX; p += 256) {
        int r = ri[a * NPIX + p];
        int slot = atomicAdd(&s_cur[r], 1);
        list[a * NPIX + slot] = (uint16_t)p;
    }
}

// ---------------- Kernel C: transposed hough, float2 lanes + 16-way split ---
// Block = (angle, q). Lane covers bc pair {2*lane, 2*lane+1} via float2
// (one 512B wave transaction per element, all 128 images). Wave w owns bins
// r = q*4 + w + 64t (<=2 bins; heavy-bin band width ~26 < 64 stride -> at
// most one heavy bin per wave). Per-wave running argmax per bc component;
// LDS merge across waves; packed atomicMax (tie -> smaller bin).
__global__ __launch_bounds__(256) void hough_T4(const float* __restrict__ pred_T,
                                                const int* __restrict__ off,
                                                const uint16_t* __restrict__ list,
                                                unsigned long long* __restrict__ pvp) {
    __shared__ uint16_t s_list[NPIX];    // 6344 B
    __shared__ int      s_off[NR + 1];
    __shared__ float    s_v0[4][64], s_v1[4][64];
    __shared__ int      s_i0[4][64], s_i1[4][64];

    const int blk  = blockIdx.x;
    const int a    = blk / NSPLIT;
    const int q    = blk - a * NSPLIT;
    const int tid  = threadIdx.x;
    const int w    = tid >> 6;
    const int lane = tid & 63;

    {   // stage full angle list (coalesced as uint32) + offsets
        const uint32_t* src = reinterpret_cast<const uint32_t*>(list + a * NPIX);
        uint32_t* dst = reinterpret_cast<uint32_t*>(s_list);
        for (int i = tid; i < NPIX / 2; i += 256) dst[i] = src[i];
        for (int r = tid; r < NR + 1; r += 256) s_off[r] = off[a * (NR + 1) + r];
    }
    __syncthreads();

    const float2* pT2 = reinterpret_cast<const float2*>(pred_T);
    float bv0 = -1.0f, bv1 = -1.0f; int bi0 = 0x7fffffff, bi1 = 0x7fffffff;
    for (int r = q * 4 + w; r < NR; r += 64) {
        int o0 = s_off[r];
        int o1 = s_off[r + 1];
        float x0 = 0, x1 = 0, x2 = 0, x3 = 0, x4 = 0, x5 = 0, x6 = 0, x7 = 0;
        float y0 = 0, y1 = 0, y2 = 0, y3 = 0, y4 = 0, y5 = 0, y6 = 0, y7 = 0;
        int j = o0;
        for (; j + 8 <= o1; j += 8) {
            float2 v0 = pT2[(int)s_list[j]     * 64 + lane];
            float2 v1 = pT2[(int)s_list[j + 1] * 64 + lane];
            float2 v2 = pT2[(int)s_list[j + 2] * 64 + lane];
            float2 v3 = pT2[(int)s_list[j + 3] * 64 + lane];
            float2 v4 = pT2[(int)s_list[j + 4] * 64 + lane];
            float2 v5 = pT2[(int)s_list[j + 5] * 64 + lane];
            float2 v6 = pT2[(int)s_list[j + 6] * 64 + lane];
            float2 v7 = pT2[(int)s_list[j + 7] * 64 + lane];
            x0 += v0.x; y0 += v0.y; x1 += v1.x; y1 += v1.y;
            x2 += v2.x; y2 += v2.y; x3 += v3.x; y3 += v3.y;
            x4 += v4.x; y4 += v4.y; x5 += v5.x; y5 += v5.y;
            x6 += v6.x; y6 += v6.y; x7 += v7.x; y7 += v7.y;
        }
        for (; j < o1; ++j) {
            float2 v = pT2[(int)s_list[j] * 64 + lane];
            x0 += v.x; y0 += v.y;
        }
        float sx = ((x0 + x1) + (x2 + x3)) + ((x4 + x5) + (x6 + x7));
        float sy = ((y0 + y1) + (y2 + y3)) + ((y4 + y5) + (y6 + y7));
        int gbin = a * NR + r;
        if (sx > bv0) { bv0 = sx; bi0 = gbin; }
        if (sy > bv1) { bv1 = sy; bi1 = gbin; }
    }
    s_v0[w][lane] = bv0; s_i0[w][lane] = bi0;
    s_v1[w][lane] = bv1; s_i1[w][lane] = bi1;
    __syncthreads();
    if (w == 0) {
        float m0 = s_v0[0][lane], m1 = s_v1[0][lane];
        int   j0 = s_i0[0][lane], j1 = s_i1[0][lane];
#pragma unroll
        for (int ww = 1; ww < 4; ++ww) {
            float o0v = s_v0[ww][lane]; int o0i = s_i0[ww][lane];
            float o1v = s_v1[ww][lane]; int o1i = s_i1[ww][lane];
            if (o0v > m0 || (o0v == m0 && o0i < j0)) { m0 = o0v; j0 = o0i; }
            if (o1v > m1 || (o1v == m1 && o1i < j1)) { m1 = o1v; j1 = o1i; }
        }
        unsigned long long e0 = ((unsigned long long)__float_as_uint(m0 < 0.f ? 0.f : m0) << 32)
                              | (unsigned long long)(65535 - j0);
        unsigned long long e1 = ((unsigned long long)__float_as_uint(m1 < 0.f ? 0.f : m1) << 32)
                              | (unsigned long long)(65535 - j1);
        atomicMax(&pvp[(2 * lane)     * NA + a], e0);
        atomicMax(&pvp[(2 * lane + 1) * NA + a], e1);
    }
}

// ---------------- Kernel D: final argmax + gather + L1-normalize + loss -----
__global__ __launch_bounds__(64) void loss_kernel(const float* __restrict__ ht,
                                                  const float* __restrict__ pexist,
                                                  const unsigned long long* __restrict__ pvp,
                                                  float* __restrict__ out) {
    const int b = blockIdx.x;
    const int l = threadIdx.x;
    const int p = l >> 2;     // pair 0..15
    const int s = l & 3;      // sub-lane within pair
    const int c = p >> 2;     // channel for ht
    const int k = p & 3;      // channel for idx/exist

    const int bck = b * 4 + k;
    unsigned long long be = 0ull;
    for (int t = 0; t < 15; ++t) {
        int a = s * 15 + t;
        unsigned long long e = pvp[bck * NA + a];
        if (e > be) be = e;
    }
#pragma unroll
    for (int m = 1; m < 4; m <<= 1) {
        unsigned long long oe = __shfl_xor(be, m);
        if (oe > be) be = oe;
    }
    int fidx = 65535 - (int)(be & 0xFFFFull);

    int a0 = fidx / NR;
    int r  = fidx - a0 * NR;
    const float* htc = ht + (size_t)((b * 4 + c) * NA) * NR;

    float acc = 0.0f;
    for (int a = s; a < NA; a += 4) acc += fabsf(htc[a * NR + r]);
    acc += __shfl_xor(acc, 1);
    acc += __shfl_xor(acc, 2);

    float term = 0.0f;
    if (s == 0) {
        float l1 = fmaxf(acc, 1e-12f);
        float gg = htc[a0 * NR + r] / l1;
        float ex = (pexist[b * 4 + k] > 0.9f) ? 1.0f : 0.0f;
        term = -logf(gg + 1e-12f) * ex;
    }
    for (int offt = 32; offt > 0; offt >>= 1) term += __shfl_down(term, offt);
    if (l == 0) out[b] = term * (1.0f / 16.0f);
}

extern "C" void kernel_launch(void* const* d_in, const int* in_sizes, int n_in,
                              void* d_out, int out_size, void* d_ws, size_t ws_size,
                              hipStream_t stream) {
    const float* ht     = (const float*)d_in[0];
    const float* pred   = (const float*)d_in[1];
    const float* pexist = (const float*)d_in[2];
    const float* vote   = (const float*)d_in[3];

    char* ws = (char*)d_ws;
    uint8_t*  ri     = (uint8_t*) (ws + WS_RI);
    int*      off    = (int*)     (ws + WS_OFF);
    uint16_t* list   = (uint16_t*)(ws + WS_LIST);
    float*    pred_T = (float*)   (ws + WS_PREDT);
    unsigned long long* pvp = (unsigned long long*)(ws + WS_PVP);

    prep<<<PRED_BLKS + GT_BLKS + ZERO_BLKS, 256, 0, stream>>>(vote, pred, ri, pred_T, pvp);
    build_csr<<<NA, 256, 0, stream>>>(ri, off, list);
    hough_T4<<<NA * NSPLIT, 256, 0, stream>>>(pred_T, off, list, pvp);
    loss_kernel<<<NB, 64, 0, stream>>>(ht, pexist, pvp, (float*)d_out);
}

// Round 10
// 46.535 us; speedup vs baseline: 4.2724x; 1.1219x over previous
//
#include <hip/hip_runtime.h>
#include <hip/hip_bf16.h>
#include <stdint.h>
#include <math.h>

#define H_HT 26
#define W_HT 122
#define NPIX (H_HT * W_HT)   // 3172
#define NA 60
#define NR 125
#define NB 32
#define NC 4
#define NBC (NB * NC)        // 128
#define PH 288
#define PW 800
#define NSPLIT 16            // rho splits per angle; wave bins r = q*4+w + 64t
#define PIX_PT 13            // ceil(3172/256) pixels per thread in csr

#define GT_BLKS ((NPIX + 1) / 2)         // 1586 transpose-gather blocks
#define ZERO_BLKS 4

// ---- workspace layout (bytes) ----
#define WS_OFF   190336                    // int32 [60*126]          30240
#define WS_LIST  220608                    // uint16[60*3172]        380640
#define WS_PREDT 601280                    // float [3172*128]      1624064
#define WS_PVP   2225344                   // u64   [128*60]          61440

// ---------------- Kernel A: fused setup -------------------------------------
// Blocks [0, NA): per-angle inline rho predict (f32, guarded-verify against
//   vote with batched independent loads + +-1 neighbor fix) + CSR build.
// Blocks [NA, NA+GT_BLKS): transpose-gather pred_T[pixel][bc].
// Last ZERO_BLKS blocks: zero pvp.
__global__ __launch_bounds__(256) void setup(const float* __restrict__ vote,
                                             const float* __restrict__ pred,
                                             int* __restrict__ off,
                                             uint16_t* __restrict__ list,
                                             float* __restrict__ pred_T,
                                             unsigned long long* __restrict__ pvp) {
    const int tid = threadIdx.x;
    if (blockIdx.x < NA) {
        const int a = blockIdx.x;
        __shared__ int s_cnt[NR];
        __shared__ int sc[2][NR];
        __shared__ int s_pre[NR + 1];
        __shared__ int s_cur[NR];

        float sn, cs;
        __sincosf((float)(a * 3) * 0.017453292519943295f, &sn, &cs);

        int  rloc[PIX_PT];
        bool grd[PIX_PT];
        // stage 1: predict (no memory)
#pragma unroll
        for (int k = 0; k < PIX_PT; ++k) {
            int p = tid + k * 256;
            rloc[k] = 0; grd[k] = false;
            if (p < NPIX) {
                int h = p / W_HT;
                int w = p - h * W_HT;
                float xs = (float)w - 60.5f;
                float ys = (float)h - 12.5f;
                float rho = xs * cs + ys * sn;
                int r = (int)rintf(rho) + NR / 2;
                r = r < 0 ? 0 : (r > NR - 1 ? NR - 1 : r);
                rloc[k] = r;
                grd[k] = fabsf(rho - floorf(rho) - 0.5f) < 1e-3f;
            }
        }
        // stage 2: batched verify reads (independent -> pipelined)
        float vv[PIX_PT];
#pragma unroll
        for (int k = 0; k < PIX_PT; ++k) {
            int p = tid + k * 256;
            vv[k] = 1.0f;
            if (p < NPIX && grd[k])
                vv[k] = vote[(size_t)(p * NA + a) * NR + rloc[k]];
        }
        // stage 3: neighbor fix (+1 then -1), rare full scan
#pragma unroll
        for (int k = 0; k < PIX_PT; ++k) {
            int p = tid + k * 256;
            if (p < NPIX && grd[k] && vv[k] == 0.0f) {
                const float* vrow = vote + (size_t)(p * NA + a) * NR;
                int r = rloc[k];
                if (r + 1 < NR && vrow[r + 1] != 0.0f) r = r + 1;
                else if (r - 1 >= 0 && vrow[r - 1] != 0.0f) r = r - 1;
                else {
                    for (int r2 = 0; r2 < NR; ++r2)
                        if (vrow[r2] != 0.0f) { r = r2; break; }
                }
                rloc[k] = r;
            }
        }
        // histogram
        for (int i = tid; i < NR; i += 256) s_cnt[i] = 0;
        __syncthreads();
#pragma unroll
        for (int k = 0; k < PIX_PT; ++k) {
            int p = tid + k * 256;
            if (p < NPIX) atomicAdd(&s_cnt[rloc[k]], 1);
        }
        __syncthreads();
        // Hillis-Steele inclusive scan over NR counters
        if (tid < NR) sc[0][tid] = s_cnt[tid];
        __syncthreads();
        int pin = 0;
        for (int d = 1; d < NR; d <<= 1) {
            if (tid < NR) {
                int v = sc[pin][tid];
                if (tid >= d) v += sc[pin][tid - d];
                sc[pin ^ 1][tid] = v;
            }
            __syncthreads();
            pin ^= 1;
        }
        if (tid == 0) s_pre[0] = 0;
        if (tid < NR) s_pre[tid + 1] = sc[pin][tid];
        __syncthreads();
        for (int r = tid; r < NR + 1; r += 256) off[a * (NR + 1) + r] = s_pre[r];
        for (int r = tid; r < NR; r += 256) s_cur[r] = s_pre[r];
        __syncthreads();
#pragma unroll
        for (int k = 0; k < PIX_PT; ++k) {
            int p = tid + k * 256;
            if (p < NPIX) {
                int slot = atomicAdd(&s_cur[rloc[k]], 1);
                list[a * NPIX + slot] = (uint16_t)p;
            }
        }
    } else if (blockIdx.x < NA + GT_BLKS) {
        const int bidx = blockIdx.x - NA;
        const int p  = bidx * 2 + (tid >> 7);
        const int bc = tid & 127;
        if (p < NPIX) {
            const float C1 = (float)(288.0 / 26.0);
            const float C2 = (float)(800.0 / 122.0);
            int h = p / W_HT;
            int w = p - h * W_HT;
            int hi = (int)floorf((float)h * C1);
            int wi = (int)floorf((float)w * C2);
            pred_T[p * NBC + bc] = pred[((size_t)bc * PH + hi) * PW + wi];
        }
    } else {
        int i0 = (blockIdx.x - NA - GT_BLKS) * 256 + tid;
        for (int i = i0; i < NA * NBC; i += ZERO_BLKS * 256) pvp[i] = 0ull;
    }
}

// ---------------- Kernel B: transposed hough, float2 lanes + 16-way split ---
__global__ __launch_bounds__(256) void hough_T4(const float* __restrict__ pred_T,
                                                const int* __restrict__ off,
                                                const uint16_t* __restrict__ list,
                                                unsigned long long* __restrict__ pvp) {
    __shared__ uint16_t s_list[NPIX];    // 6344 B
    __shared__ int      s_off[NR + 1];
    __shared__ float    s_v0[4][64], s_v1[4][64];
    __shared__ int      s_i0[4][64], s_i1[4][64];

    const int blk  = blockIdx.x;
    const int a    = blk / NSPLIT;
    const int q    = blk - a * NSPLIT;
    const int tid  = threadIdx.x;
    const int w    = tid >> 6;
    const int lane = tid & 63;

    {   // stage full angle list (coalesced as uint32) + offsets
        const uint32_t* src = reinterpret_cast<const uint32_t*>(list + a * NPIX);
        uint32_t* dst = reinterpret_cast<uint32_t*>(s_list);
        for (int i = tid; i < NPIX / 2; i += 256) dst[i] = src[i];
        for (int r = tid; r < NR + 1; r += 256) s_off[r] = off[a * (NR + 1) + r];
    }
    __syncthreads();

    const float2* pT2 = reinterpret_cast<const float2*>(pred_T);
    float bv0 = -1.0f, bv1 = -1.0f; int bi0 = 0x7fffffff, bi1 = 0x7fffffff;
    for (int r = q * 4 + w; r < NR; r += 64) {
        int o0 = s_off[r];
        int o1 = s_off[r + 1];
        float x0 = 0, x1 = 0, x2 = 0, x3 = 0, x4 = 0, x5 = 0, x6 = 0, x7 = 0;
        float y0 = 0, y1 = 0, y2 = 0, y3 = 0, y4 = 0, y5 = 0, y6 = 0, y7 = 0;
        int j = o0;
        for (; j + 8 <= o1; j += 8) {
            float2 v0 = pT2[(int)s_list[j]     * 64 + lane];
            float2 v1 = pT2[(int)s_list[j + 1] * 64 + lane];
            float2 v2 = pT2[(int)s_list[j + 2] * 64 + lane];
            float2 v3 = pT2[(int)s_list[j + 3] * 64 + lane];
            float2 v4 = pT2[(int)s_list[j + 4] * 64 + lane];
            float2 v5 = pT2[(int)s_list[j + 5] * 64 + lane];
            float2 v6 = pT2[(int)s_list[j + 6] * 64 + lane];
            float2 v7 = pT2[(int)s_list[j + 7] * 64 + lane];
            x0 += v0.x; y0 += v0.y; x1 += v1.x; y1 += v1.y;
            x2 += v2.x; y2 += v2.y; x3 += v3.x; y3 += v3.y;
            x4 += v4.x; y4 += v4.y; x5 += v5.x; y5 += v5.y;
            x6 += v6.x; y6 += v6.y; x7 += v7.x; y7 += v7.y;
        }
        for (; j < o1; ++j) {
            float2 v = pT2[(int)s_list[j] * 64 + lane];
            x0 += v.x; y0 += v.y;
        }
        float sx = ((x0 + x1) + (x2 + x3)) + ((x4 + x5) + (x6 + x7));
        float sy = ((y0 + y1) + (y2 + y3)) + ((y4 + y5) + (y6 + y7));
        int gbin = a * NR + r;
        if (sx > bv0) { bv0 = sx; bi0 = gbin; }
        if (sy > bv1) { bv1 = sy; bi1 = gbin; }
    }
    s_v0[w][lane] = bv0; s_i0[w][lane] = bi0;
    s_v1[w][lane] = bv1; s_i1[w][lane] = bi1;
    __syncthreads();
    if (w == 0) {
        float m0 = s_v0[0][lane], m1 = s_v1[0][lane];
        int   j0 = s_i0[0][lane], j1 = s_i1[0][lane];
#pragma unroll
        for (int ww = 1; ww < 4; ++ww) {
            float o0v = s_v0[ww][lane]; int o0i = s_i0[ww][lane];
            float o1v = s_v1[ww][lane]; int o1i = s_i1[ww][lane];
            if (o0v > m0 || (o0v == m0 && o0i < j0)) { m0 = o0v; j0 = o0i; }
            if (o1v > m1 || (o1v == m1 && o1i < j1)) { m1 = o1v; j1 = o1i; }
        }
        unsigned long long e0 = ((unsigned long long)__float_as_uint(m0 < 0.f ? 0.f : m0) << 32)
                              | (unsigned long long)(65535 - j0);
        unsigned long long e1 = ((unsigned long long)__float_as_uint(m1 < 0.f ? 0.f : m1) << 32)
                              | (unsigned long long)(65535 - j1);
        atomicMax(&pvp[(2 * lane)     * NA + a], e0);
        atomicMax(&pvp[(2 * lane + 1) * NA + a], e1);
    }
}

// ---------------- Kernel C: final argmax + gather + L1-normalize + loss -----
__global__ __launch_bounds__(64) void loss_kernel(const float* __restrict__ ht,
                                                  const float* __restrict__ pexist,
                                                  const unsigned long long* __restrict__ pvp,
                                                  float* __restrict__ out) {
    const int b = blockIdx.x;
    const int l = threadIdx.x;
    const int p = l >> 2;     // pair 0..15
    const int s = l & 3;      // sub-lane within pair
    const int c = p >> 2;     // channel for ht
    const int k = p & 3;      // channel for idx/exist

    const int bck = b * 4 + k;
    unsigned long long be = 0ull;
    for (int t = 0; t < 15; ++t) {
        int a = s * 15 + t;
        unsigned long long e = pvp[bck * NA + a];
        if (e > be) be = e;
    }
#pragma unroll
    for (int m = 1; m < 4; m <<= 1) {
        unsigned long long oe = __shfl_xor(be, m);
        if (oe > be) be = oe;
    }
    int fidx = 65535 - (int)(be & 0xFFFFull);

    int a0 = fidx / NR;
    int r  = fidx - a0 * NR;
    const float* htc = ht + (size_t)((b * 4 + c) * NA) * NR;

    float acc = 0.0f;
    for (int a = s; a < NA; a += 4) acc += fabsf(htc[a * NR + r]);
    acc += __shfl_xor(acc, 1);
    acc += __shfl_xor(acc, 2);

    float term = 0.0f;
    if (s == 0) {
        float l1 = fmaxf(acc, 1e-12f);
        float gg = htc[a0 * NR + r] / l1;
        float ex = (pexist[b * 4 + k] > 0.9f) ? 1.0f : 0.0f;
        term = -logf(gg + 1e-12f) * ex;
    }
    for (int offt = 32; offt > 0; offt >>= 1) term += __shfl_down(term, offt);
    if (l == 0) out[b] = term * (1.0f / 16.0f);
}

extern "C" void kernel_launch(void* const* d_in, const int* in_sizes, int n_in,
                              void* d_out, int out_size, void* d_ws, size_t ws_size,
                              hipStream_t stream) {
    const float* ht     = (const float*)d_in[0];
    const float* pred   = (const float*)d_in[1];
    const float* pexist = (const float*)d_in[2];
    const float* vote   = (const float*)d_in[3];

    char* ws = (char*)d_ws;
    int*      off    = (int*)     (ws + WS_OFF);
    uint16_t* list   = (uint16_t*)(ws + WS_LIST);
    float*    pred_T = (float*)   (ws + WS_PREDT);
    unsigned long long* pvp = (unsigned long long*)(ws + WS_PVP);

    setup<<<NA + GT_BLKS + ZERO_BLKS, 256, 0, stream>>>(vote, pred, off, list, pred_T, pvp);
    hough_T4<<<NA * NSPLIT, 256, 0, stream>>>(pred_T, off, list, pvp);
    loss_kernel<<<NB, 64, 0, stream>>>(ht, pexist, pvp, (float*)d_out);
}